// Round 3
// baseline (200.193 us; speedup 1.0000x reference)
//
#include <hip/hip_runtime.h>

#define NB 4096     // batch
#define ND 512      // dim
#define P2_BLOCKS 1024
#define P2_ROWS 4   // rows per pass-2 block

typedef __bf16 bf16x8 __attribute__((ext_vector_type(8)));
typedef unsigned short u16x8 __attribute__((ext_vector_type(8)));
typedef _Float16 f16x8 __attribute__((ext_vector_type(8)));
typedef _Float16 f16x4 __attribute__((ext_vector_type(4)));
typedef float f32x4 __attribute__((ext_vector_type(4)));

__device__ inline unsigned short f2bf(float f){
  unsigned u = __float_as_uint(f);
  u += 0x7FFFu + ((u >> 16) & 1u);      // round-to-nearest-even
  return (unsigned short)(u >> 16);
}

// async global->LDS, 16B per lane. LDS dest = wave-uniform base + lane*16.
__device__ inline void gl2lds16(const unsigned short* g, unsigned short* l){
  __builtin_amdgcn_global_load_lds(
      (const __attribute__((address_space(1))) unsigned int*)g,
      (__attribute__((address_space(3))) unsigned int*)l, 16, 0, 0);
}

// fused: feats fp32 -> bf16; zero the pass-2 completion counter
__global__ __launch_bounds__(256) void convert_init(const float* feats, unsigned short* fb,
                                                    unsigned* counter){
  size_t idx = (size_t)blockIdx.x * 256 + threadIdx.x;  // group of 8 elements
  const float4* p = (const float4*)(feats + idx * 8);
  float4 x0 = p[0], x1 = p[1];
  u16x8 v;
  v[0]=f2bf(x0.x); v[1]=f2bf(x0.y); v[2]=f2bf(x0.z); v[3]=f2bf(x0.w);
  v[4]=f2bf(x1.x); v[5]=f2bf(x1.y); v[6]=f2bf(x1.z); v[7]=f2bf(x1.w);
  *(u16x8*)(fb + idx * 8) = v;
  if (blockIdx.x == 0 && threadIdx.x == 0) counter[0] = 0;
}

// PASS 1: pure GEMM sim = F F^T (bf16 in, fp32 acc, fp16 out), 128x128 tile,
// 4 waves, 4x4 16x16x32-MFMA frags, BK=32, global_load_lds width-16 staging.
// Symmetry: only upper-triangle blocks (bx>=by) compute; off-diag blocks store
// tile AND transposed tile (dot products are bitwise-commutative, so the
// mirrored value is identical to what the skipped block would compute).
__global__ __launch_bounds__(256) void gemm_sim(const unsigned short* fb, _Float16* sim){
  __shared__ unsigned short As[128*32];
  __shared__ unsigned short Bs[128*32];

  const int bx = blockIdx.x;   // col block
  const int by = blockIdx.y;   // row block
  if (bx < by) return;         // lower triangle: mirrored by (by,bx)

  const int tid  = threadIdx.x;
  const int lane = tid & 63;
  const int wave = tid >> 6;
  const int m0   = (wave >> 1) * 64;
  const int n0   = (wave & 1) * 64;
  const int quad = lane >> 4;
  const int l15  = lane & 15;

  // staging: wave w owns rows [w*32, w*32+32), 2 chunks of 16 rows;
  // lane l -> row l/4, col (l%4)*8 (LDS byte offset = 16*l from chunk base)
  const int srow = lane >> 2;
  const int scol = (lane & 3) * 8;
  const unsigned short* aseg = fb + (size_t)(by*128 + wave*32 + srow) * ND + scol;
  const unsigned short* bseg = fb + (size_t)(bx*128 + wave*32 + srow) * ND + scol;
  unsigned short* abase = &As[(wave*32) * 32];
  unsigned short* bbase = &Bs[(wave*32) * 32];

  f32x4 acc[4][4];
#pragma unroll
  for (int i=0;i<4;++i)
#pragma unroll
    for (int j=0;j<4;++j) acc[i][j] = (f32x4){0.f,0.f,0.f,0.f};

  for (int k0 = 0; k0 < ND; k0 += 32){
    __syncthreads();
#pragma unroll
    for (int c = 0; c < 2; ++c){
      gl2lds16(aseg + k0 + c*16*ND, abase + c*16*32);
      gl2lds16(bseg + k0 + c*16*ND, bbase + c*16*32);
    }
    __syncthreads();

    bf16x8 af[4], bfr[4];
#pragma unroll
    for (int s = 0; s < 4; ++s){
      af[s]  = __builtin_bit_cast(bf16x8, *(const u16x8*)&As[(m0 + s*16 + l15)*32 + quad*8]);
      bfr[s] = __builtin_bit_cast(bf16x8, *(const u16x8*)&Bs[(n0 + s*16 + l15)*32 + quad*8]);
    }
#pragma unroll
    for (int sm=0;sm<4;++sm)
#pragma unroll
      for (int sn=0;sn<4;++sn)
        acc[sm][sn] = __builtin_amdgcn_mfma_f32_16x16x32_bf16(af[sm], bfr[sn], acc[sm][sn], 0, 0, 0);
  }

  // store epilogue. C/D layout: col = lane&15, row = quad*4 + reg per 16x16 subtile.
#pragma unroll
  for (int sm=0;sm<4;++sm){
    const int R0 = by*128 + m0 + sm*16 + quad*4;   // 4 consecutive rows R0..R0+3
#pragma unroll
    for (int sn=0;sn<4;++sn){
      const int C = bx*128 + n0 + sn*16 + l15;
      f16x4 h;
#pragma unroll
      for (int reg=0;reg<4;++reg) h[reg] = (_Float16)acc[sm][sn][reg];
      // direct: 4 stores (rows R0+reg, col C) -> 16 cols/quad-row contiguous across lanes
#pragma unroll
      for (int reg=0;reg<4;++reg)
        __builtin_nontemporal_store(h[reg], sim + (size_t)(R0+reg)*NB + C);
      // mirror: one 8B store of 4 consecutive elements in row C
      if (bx != by)
        __builtin_nontemporal_store(h, (f16x4*)(sim + (size_t)C*NB + R0));
    }
  }
}

// PASS 2: stream sim rows; compute ALL row stats in-register (two phases over
// the same registers), accumulate block loss; last block reduces to out[0].
__global__ __launch_bounds__(256) void row_stats(const _Float16* sim, const int* labels,
                                                 float* blockLoss, unsigned* counter, float* out){
  const int tid  = threadIdx.x;
  const int lane = tid & 63;
  const int wv   = tid >> 6;
  __shared__ float redA[3][4], redB[3][4];
  __shared__ unsigned sFlag;

  // my 16 fixed columns: c0..c0+7 and 2048+c0..+7
  const int c0 = tid * 8;
  int lab[16];
  {
    const int4* lp  = (const int4*)(labels + c0);
    const int4* lp2 = (const int4*)(labels + 2048 + c0);
    int4 a = lp[0], b = lp[1], c = lp2[0], d = lp2[1];
    lab[0]=a.x; lab[1]=a.y; lab[2]=a.z; lab[3]=a.w;
    lab[4]=b.x; lab[5]=b.y; lab[6]=b.z; lab[7]=b.w;
    lab[8]=c.x; lab[9]=c.y; lab[10]=c.z; lab[11]=c.w;
    lab[12]=d.x; lab[13]=d.y; lab[14]=d.z; lab[15]=d.w;
  }

  float loss_acc = 0.f;

  for (int rr = 0; rr < P2_ROWS; ++rr){
    const int r = blockIdx.x * P2_ROWS + rr;
    const int labR = labels[r];                    // wave-uniform
    const _Float16* rowp = sim + (size_t)r * NB;
    f16x8 h0 = __builtin_nontemporal_load((const f16x8*)(rowp + c0));
    f16x8 h1 = __builtin_nontemporal_load((const f16x8*)(rowp + 2048 + c0));
    float v[16];
#pragma unroll
    for (int j=0;j<8;++j){ v[j] = (float)h0[j]; v[8+j] = (float)h1[j]; }

    // phase A: sum, min_pos (same & <1-eps), max_neg (diff)
    float s = 0.f, mp = 3.0e38f, mn = -3.0e38f;
#pragma unroll
    for (int j=0;j<16;++j){
      const float x = v[j];
      s += x;
      if (lab[j] == labR){ if (x < 0.99999f) mp = fminf(mp, x); }
      else               { mn = fmaxf(mn, x); }
    }
#pragma unroll
    for (int o=1;o<64;o<<=1){
      s  += __shfl_xor(s, o, 64);
      mp  = fminf(mp, __shfl_xor(mp, o, 64));
      mn  = fmaxf(mn, __shfl_xor(mn, o, 64));
    }
    if (lane == 0){ redA[0][wv] = s; redA[1][wv] = mp; redA[2][wv] = mn; }
    __syncthreads();
    float S = 0.f, MP = 3.0e38f, MN = -3.0e38f;
#pragma unroll
    for (int w=0;w<4;++w){
      S += redA[0][w]; MP = fminf(MP, redA[1][w]); MN = fmaxf(MN, redA[2][w]);
    }
    const bool hp = (MP < 1.0e38f), hn = (MN > -1.0e38f);
    const float mpr = hp ? MP : 1.0e9f;            // BIG like reference
    const float mnr = hn ? MN : -1.0e9f;
    const float mean_ = (S * (1.0f/(float)NB) + 0.5f*(mpr+mnr)) * 0.5f;
    const float tpp = mnr + 0.1f;                  // pp: x < max_neg + MARGIN
    const float tnm = mpr - 0.1f;                  // nm: x > min_pos - MARGIN

    // phase B: sigma, fp, fn from the same registers
    float sg = 0.f, fps = 0.f, fns = 0.f;
#pragma unroll
    for (int j=0;j<16;++j){
      const float x = v[j];
      if (lab[j] != labR){
        const float d = x - mean_; sg += d*d;
        if (x > tnm) fns += __expf((x - 0.5f) * 40.0f);
      } else if (x < 0.99999f && x < tpp){
        fps += __expf(-(x - 0.5f) * 2.0f);
      }
    }
#pragma unroll
    for (int o=1;o<64;o<<=1){
      sg  += __shfl_xor(sg,  o, 64);
      fps += __shfl_xor(fps, o, 64);
      fns += __shfl_xor(fns, o, 64);
    }
    if (lane == 0){ redB[0][wv] = sg; redB[1][wv] = fps; redB[2][wv] = fns; }
    __syncthreads();
    if (tid == 0){
      float SG = redB[0][0]+redB[0][1]+redB[0][2]+redB[0][3];
      float FPS = redB[1][0]+redB[1][1]+redB[1][2]+redB[1][3];
      float FNS = redB[2][0]+redB[2][1]+redB[2][2]+redB[2][3];
      if (hp && hn && FPS > 0.f && FNS > 0.f)
        loss_acc += logf(1.f + FPS) + logf(1.f + FNS) + 0.1f * SG;
    }
    __syncthreads();   // redA/redB reused next row
  }

  if (tid == 0) blockLoss[blockIdx.x] = loss_acc;
  __threadfence();
  if (tid == 0) sFlag = atomicAdd(counter, 1);
  __syncthreads();

  if (sFlag == (unsigned)(gridDim.x - 1)){   // last block: final reduction
    __threadfence();
    float l = 0.f;
    for (int i = tid; i < P2_BLOCKS; i += 256) l += blockLoss[i];
#pragma unroll
    for (int o=1;o<64;o<<=1) l += __shfl_xor(l, o, 64);
    if (lane == 0) redA[0][wv] = l;
    __syncthreads();
    if (tid == 0)
      out[0] = (redA[0][0]+redA[0][1]+redA[0][2]+redA[0][3]) * (1.0f/(float)NB);
  }
}

extern "C" void kernel_launch(void* const* d_in, const int* in_sizes, int n_in,
                              void* d_out, int out_size, void* d_ws, size_t ws_size,
                              hipStream_t stream) {
  (void)in_sizes; (void)n_in; (void)out_size; (void)ws_size;
  const float* feats  = (const float*)d_in[0];
  const int*   labels = (const int*)d_in[1];
  float* out = (float*)d_out;

  // ws layout: sim fp16 (32MB) | fb bf16 (4MB) | blockLoss (4KB) | counter
  _Float16* sim       = (_Float16*)d_ws;
  unsigned short* fb  = (unsigned short*)(sim + (size_t)NB*NB);
  float* blockLoss    = (float*)(fb + (size_t)NB*ND);
  unsigned* counter   = (unsigned*)(blockLoss + P2_BLOCKS);

  convert_init<<<dim3((NB*ND/8)/256), dim3(256), 0, stream>>>(feats, fb, counter);

  dim3 grid(NB/128, NB/128);
  gemm_sim<<<grid, dim3(256), 0, stream>>>(fb, sim);

  row_stats<<<dim3(P2_BLOCKS), dim3(256), 0, stream>>>(sim, labels, blockLoss, counter, out);
}

// Round 4
// 154.667 us; speedup vs baseline: 1.2943x; 1.2943x over previous
//
#include <hip/hip_runtime.h>

#define NB 4096     // batch
#define ND 512      // dim

typedef __bf16 bf16x8 __attribute__((ext_vector_type(8)));
typedef unsigned short u16x8 __attribute__((ext_vector_type(8)));
typedef _Float16 f16x8 __attribute__((ext_vector_type(8)));
typedef _Float16 f16x4 __attribute__((ext_vector_type(4)));
typedef float f32x4 __attribute__((ext_vector_type(4)));

__device__ inline unsigned short f2bf(float f){
  unsigned u = __float_as_uint(f);
  u += 0x7FFFu + ((u >> 16) & 1u);      // round-to-nearest-even
  return (unsigned short)(u >> 16);
}

// async global->LDS, 16B per lane. LDS dest = wave-uniform base + lane*16.
__device__ inline void gl2lds16(const unsigned short* g, unsigned short* l){
  __builtin_amdgcn_global_load_lds(
      (const __attribute__((address_space(1))) unsigned int*)g,
      (__attribute__((address_space(3))) unsigned int*)l, 16, 0, 0);
}

// fused: feats fp32 -> bf16; block 0 also packs labels->u8 and zeroes out[0]
__global__ __launch_bounds__(256) void convert_init(const float* feats, unsigned short* fb,
                                                    const int* labels, unsigned char* lab8,
                                                    float* out){
  size_t idx = (size_t)blockIdx.x * 256 + threadIdx.x;  // group of 8 elements
  const float4* p = (const float4*)(feats + idx * 8);
  float4 x0 = p[0], x1 = p[1];
  u16x8 v;
  v[0]=f2bf(x0.x); v[1]=f2bf(x0.y); v[2]=f2bf(x0.z); v[3]=f2bf(x0.w);
  v[4]=f2bf(x1.x); v[5]=f2bf(x1.y); v[6]=f2bf(x1.z); v[7]=f2bf(x1.w);
  *(u16x8*)(fb + idx * 8) = v;

  if (blockIdx.x == 0){
    // pack 16 labels per thread (labels < 256)
    const int t = threadIdx.x;
    const int4* lp = (const int4*)(labels + t*16);
    int4 a = lp[0], b = lp[1], c = lp[2], d = lp[3];
    unsigned char pk[16] = {
      (unsigned char)a.x,(unsigned char)a.y,(unsigned char)a.z,(unsigned char)a.w,
      (unsigned char)b.x,(unsigned char)b.y,(unsigned char)b.z,(unsigned char)b.w,
      (unsigned char)c.x,(unsigned char)c.y,(unsigned char)c.z,(unsigned char)c.w,
      (unsigned char)d.x,(unsigned char)d.y,(unsigned char)d.z,(unsigned char)d.w };
    *(int4*)(lab8 + t*16) = *(const int4*)pk;
    if (t == 0) out[0] = 0.f;
  }
}

// PASS 1: pure GEMM sim = F F^T (bf16 in, fp32 acc, fp16 out), 128x128 tile,
// 4 waves, 4x4 16x16x32-MFMA frags, BK=32, global_load_lds width-16 staging.
// Symmetry: only upper-triangle blocks (bx>=by); off-diag blocks store tile
// AND its transpose (dot products bitwise-commutative). CACHED stores: L2
// merges the 2B scalar stores, and pass 2 wants sim resident in L2/L3.
__global__ __launch_bounds__(256) void gemm_sim(const unsigned short* fb, _Float16* sim){
  __shared__ unsigned short As[128*32];
  __shared__ unsigned short Bs[128*32];

  const int bx = blockIdx.x;   // col block
  const int by = blockIdx.y;   // row block
  if (bx < by) return;         // lower triangle: mirrored by (by,bx)

  const int tid  = threadIdx.x;
  const int lane = tid & 63;
  const int wave = tid >> 6;
  const int m0   = (wave >> 1) * 64;
  const int n0   = (wave & 1) * 64;
  const int quad = lane >> 4;
  const int l15  = lane & 15;

  const int srow = lane >> 2;
  const int scol = (lane & 3) * 8;
  const unsigned short* aseg = fb + (size_t)(by*128 + wave*32 + srow) * ND + scol;
  const unsigned short* bseg = fb + (size_t)(bx*128 + wave*32 + srow) * ND + scol;
  unsigned short* abase = &As[(wave*32) * 32];
  unsigned short* bbase = &Bs[(wave*32) * 32];

  f32x4 acc[4][4];
#pragma unroll
  for (int i=0;i<4;++i)
#pragma unroll
    for (int j=0;j<4;++j) acc[i][j] = (f32x4){0.f,0.f,0.f,0.f};

  for (int k0 = 0; k0 < ND; k0 += 32){
    __syncthreads();
#pragma unroll
    for (int c = 0; c < 2; ++c){
      gl2lds16(aseg + k0 + c*16*ND, abase + c*16*32);
      gl2lds16(bseg + k0 + c*16*ND, bbase + c*16*32);
    }
    __syncthreads();

    bf16x8 af[4], bfr[4];
#pragma unroll
    for (int s = 0; s < 4; ++s){
      af[s]  = __builtin_bit_cast(bf16x8, *(const u16x8*)&As[(m0 + s*16 + l15)*32 + quad*8]);
      bfr[s] = __builtin_bit_cast(bf16x8, *(const u16x8*)&Bs[(n0 + s*16 + l15)*32 + quad*8]);
    }
#pragma unroll
    for (int sm=0;sm<4;++sm)
#pragma unroll
      for (int sn=0;sn<4;++sn)
        acc[sm][sn] = __builtin_amdgcn_mfma_f32_16x16x32_bf16(af[sm], bfr[sn], acc[sm][sn], 0, 0, 0);
  }

  // store epilogue. C/D layout: col = lane&15, row = quad*4 + reg per 16x16 subtile.
#pragma unroll
  for (int sm=0;sm<4;++sm){
    const int R0 = by*128 + m0 + sm*16 + quad*4;   // 4 consecutive rows
#pragma unroll
    for (int sn=0;sn<4;++sn){
      const int C = bx*128 + n0 + sn*16 + l15;
      f16x4 h;
#pragma unroll
      for (int reg=0;reg<4;++reg) h[reg] = (_Float16)acc[sm][sn][reg];
#pragma unroll
      for (int reg=0;reg<4;++reg)
        sim[(size_t)(R0+reg)*NB + C] = h[reg];           // L2 merges to full lines
      if (bx != by)
        *(f16x4*)(sim + (size_t)C*NB + R0) = h;          // transpose mirror, 8B
    }
  }
}

// PASS 2: one row per WAVE, no in-loop barriers. Wave loads its whole row
// (64 fp16/lane in 8 vec loads, all independent), phase A reduce (butterfly
// leaves totals in every lane -> thresholds wave-uniform for free), phase B
// over the same registers, one atomicAdd per row.
__global__ __launch_bounds__(256) void row_stats(const _Float16* sim, const unsigned char* lab8,
                                                 const int* labels, float* out){
  __shared__ unsigned char slab[NB];   // 4 KB: all labels as bytes
  const int tid  = threadIdx.x;
  *(int4*)&slab[tid*16] = *(const int4*)&lab8[tid*16];
  __syncthreads();

  const int lane = tid & 63;
  const int wv   = tid >> 6;
  const int r    = blockIdx.x * 4 + wv;
  const int labR = labels[r];                       // uniform -> s_load
  const _Float16* rowp = sim + (size_t)r * NB;

  // load whole row: chunk c covers cols c*512 + lane*8 .. +7
  f16x8 h[8];
  unsigned long long lb[8];
#pragma unroll
  for (int c=0;c<8;++c)
    h[c] = *(const f16x8*)(rowp + c*512 + lane*8);
#pragma unroll
  for (int c=0;c<8;++c)
    lb[c] = *(const unsigned long long*)&slab[c*512 + lane*8];

  // phase A: sum, min_pos (same & <1-eps), max_neg (diff)
  float s = 0.f, mp = 3.0e38f, mn = -3.0e38f;
#pragma unroll
  for (int c=0;c<8;++c){
    const unsigned long long L = lb[c];
#pragma unroll
    for (int j=0;j<8;++j){
      const float x = (float)h[c][j];
      const int lj = (int)((L >> (8*j)) & 0xffULL);
      s += x;
      if (lj == labR){ if (x < 0.99999f) mp = fminf(mp, x); }
      else           { mn = fmaxf(mn, x); }
    }
  }
#pragma unroll
  for (int o=1;o<64;o<<=1){
    s  += __shfl_xor(s, o, 64);
    mp  = fminf(mp, __shfl_xor(mp, o, 64));
    mn  = fmaxf(mn, __shfl_xor(mn, o, 64));
  }
  const bool hp = (mp < 1.0e38f), hn = (mn > -1.0e38f);
  const float mpr = hp ? mp : 1.0e9f;               // BIG like reference
  const float mnr = hn ? mn : -1.0e9f;
  const float mean_ = (s * (1.0f/(float)NB) + 0.5f*(mpr+mnr)) * 0.5f;
  const float tpp = mnr + 0.1f;                     // pp: x < max_neg + MARGIN
  const float tnm = mpr - 0.1f;                     // nm: x > min_pos - MARGIN

  // phase B: sigma, fp, fn from the same registers
  float sg = 0.f, fps = 0.f, fns = 0.f;
#pragma unroll
  for (int c=0;c<8;++c){
    const unsigned long long L = lb[c];
#pragma unroll
    for (int j=0;j<8;++j){
      const float x = (float)h[c][j];
      const int lj = (int)((L >> (8*j)) & 0xffULL);
      if (lj != labR){
        const float d = x - mean_; sg += d*d;
        if (x > tnm) fns += __expf((x - 0.5f) * 40.0f);
      } else if (x < 0.99999f && x < tpp){
        fps += __expf(-(x - 0.5f) * 2.0f);
      }
    }
  }
#pragma unroll
  for (int o=1;o<64;o<<=1){
    sg  += __shfl_xor(sg,  o, 64);
    fps += __shfl_xor(fps, o, 64);
    fns += __shfl_xor(fns, o, 64);
  }

  if (lane == 0 && hp && hn && fps > 0.f && fns > 0.f){
    const float loss = logf(1.f + fps) + logf(1.f + fns) + 0.1f * sg;
    atomicAdd(out, loss * (1.0f/(float)NB));
  }
}

extern "C" void kernel_launch(void* const* d_in, const int* in_sizes, int n_in,
                              void* d_out, int out_size, void* d_ws, size_t ws_size,
                              hipStream_t stream) {
  (void)in_sizes; (void)n_in; (void)out_size; (void)ws_size;
  const float* feats  = (const float*)d_in[0];
  const int*   labels = (const int*)d_in[1];
  float* out = (float*)d_out;

  // ws layout: sim fp16 (32MB) | fb bf16 (4MB) | lab8 (4KB)
  _Float16* sim       = (_Float16*)d_ws;
  unsigned short* fb  = (unsigned short*)(sim + (size_t)NB*NB);
  unsigned char* lab8 = (unsigned char*)(fb + (size_t)NB*ND);

  convert_init<<<dim3((NB*ND/8)/256), dim3(256), 0, stream>>>(feats, fb, labels, lab8, out);

  dim3 grid(NB/128, NB/128);
  gemm_sim<<<grid, dim3(256), 0, stream>>>(fb, sim);

  row_stats<<<dim3(NB/4), dim3(256), 0, stream>>>(sim, lab8, labels, out);
}

// Round 5
// 104.582 us; speedup vs baseline: 1.9142x; 1.4789x over previous
//
#include <hip/hip_runtime.h>
#include <math.h>

#define NB 4096     // batch
#define ND 512      // dim

typedef __bf16 bf16x8 __attribute__((ext_vector_type(8)));
typedef unsigned short u16x8 __attribute__((ext_vector_type(8)));
typedef _Float16 f16x8 __attribute__((ext_vector_type(8)));
typedef _Float16 f16x4 __attribute__((ext_vector_type(4)));
typedef float f32x4 __attribute__((ext_vector_type(4)));

__device__ inline unsigned short f2bf(float f){
  unsigned u = __float_as_uint(f);
  u += 0x7FFFu + ((u >> 16) & 1u);      // round-to-nearest-even
  return (unsigned short)(u >> 16);
}

// async global->LDS, 16B per lane. LDS dest = wave-uniform base + lane*16.
__device__ inline void gl2lds16(const unsigned short* g, unsigned short* l){
  __builtin_amdgcn_global_load_lds(
      (const __attribute__((address_space(1))) unsigned int*)g,
      (__attribute__((address_space(3))) unsigned int*)l, 16, 0, 0);
}

// fused: feats fp32 -> bf16; block 0 also packs labels->u8 (C=256 fits a byte)
__global__ __launch_bounds__(256) void convert_init(const float* feats, unsigned short* fb,
                                                    const int* labels, unsigned char* lab8){
  size_t idx = (size_t)blockIdx.x * 256 + threadIdx.x;  // group of 8 elements
  const float4* p = (const float4*)(feats + idx * 8);
  float4 x0 = p[0], x1 = p[1];
  u16x8 v;
  v[0]=f2bf(x0.x); v[1]=f2bf(x0.y); v[2]=f2bf(x0.z); v[3]=f2bf(x0.w);
  v[4]=f2bf(x1.x); v[5]=f2bf(x1.y); v[6]=f2bf(x1.z); v[7]=f2bf(x1.w);
  *(u16x8*)(fb + idx * 8) = v;

  if (blockIdx.x == 0){
    const int t = threadIdx.x;
    const int4* lp = (const int4*)(labels + t*16);
    int4 a = lp[0], b = lp[1], c = lp[2], d = lp[3];
    unsigned char pk[16] = {
      (unsigned char)a.x,(unsigned char)a.y,(unsigned char)a.z,(unsigned char)a.w,
      (unsigned char)b.x,(unsigned char)b.y,(unsigned char)b.z,(unsigned char)b.w,
      (unsigned char)c.x,(unsigned char)c.y,(unsigned char)c.z,(unsigned char)c.w,
      (unsigned char)d.x,(unsigned char)d.y,(unsigned char)d.z,(unsigned char)d.w };
    *(int4*)(lab8 + t*16) = *(const int4*)pk;
  }
}

// PASS 1: sim = F F^T (bf16 in, fp32 acc, fp16 out), 128x128 tile, 4 waves,
// 4x4 16x16x32-MFMA frags, BK=32, global_load_lds width-16 staging.
// Grid: 528 linear blocks = upper triangle only; off-diag blocks store the
// tile AND its transpose (dot products are bitwise-commutative).
__global__ __launch_bounds__(256) void gemm_sim(const unsigned short* fb, _Float16* sim){
  __shared__ unsigned short As[128*32];
  __shared__ unsigned short Bs[128*32];

  // triangular decode: t -> (by, bx), bx >= by, 32 blocks/dim
  const int t  = blockIdx.x;
  const int by = (int)((65.0 - sqrt(4225.0 - 8.0*(double)t)) * 0.5);
  const int bx = by + t - (by*(65 - by))/2;

  const int tid  = threadIdx.x;
  const int lane = tid & 63;
  const int wave = tid >> 6;
  const int m0   = (wave >> 1) * 64;
  const int n0   = (wave & 1) * 64;
  const int quad = lane >> 4;
  const int l15  = lane & 15;

  const int srow = lane >> 2;
  const int scol = (lane & 3) * 8;
  const unsigned short* aseg = fb + (size_t)(by*128 + wave*32 + srow) * ND + scol;
  const unsigned short* bseg = fb + (size_t)(bx*128 + wave*32 + srow) * ND + scol;
  unsigned short* abase = &As[(wave*32) * 32];
  unsigned short* bbase = &Bs[(wave*32) * 32];

  f32x4 acc[4][4];
#pragma unroll
  for (int i=0;i<4;++i)
#pragma unroll
    for (int j=0;j<4;++j) acc[i][j] = (f32x4){0.f,0.f,0.f,0.f};

  for (int k0 = 0; k0 < ND; k0 += 32){
    __syncthreads();
#pragma unroll
    for (int c = 0; c < 2; ++c){
      gl2lds16(aseg + k0 + c*16*ND, abase + c*16*32);
      gl2lds16(bseg + k0 + c*16*ND, bbase + c*16*32);
    }
    __syncthreads();

    bf16x8 af[4], bfr[4];
#pragma unroll
    for (int s = 0; s < 4; ++s){
      af[s]  = __builtin_bit_cast(bf16x8, *(const u16x8*)&As[(m0 + s*16 + l15)*32 + quad*8]);
      bfr[s] = __builtin_bit_cast(bf16x8, *(const u16x8*)&Bs[(n0 + s*16 + l15)*32 + quad*8]);
    }
#pragma unroll
    for (int sm=0;sm<4;++sm)
#pragma unroll
      for (int sn=0;sn<4;++sn)
        acc[sm][sn] = __builtin_amdgcn_mfma_f32_16x16x32_bf16(af[sm], bfr[sn], acc[sm][sn], 0, 0, 0);
  }

  // store epilogue. C/D layout: col = lane&15, row = quad*4 + reg per 16x16 subtile.
#pragma unroll
  for (int sm=0;sm<4;++sm){
    const int R0 = by*128 + m0 + sm*16 + quad*4;   // 4 consecutive rows
#pragma unroll
    for (int sn=0;sn<4;++sn){
      const int C = bx*128 + n0 + sn*16 + l15;
      f16x4 h;
#pragma unroll
      for (int reg=0;reg<4;++reg) h[reg] = (_Float16)acc[sm][sn][reg];
#pragma unroll
      for (int reg=0;reg<4;++reg)
        sim[(size_t)(R0+reg)*NB + C] = h[reg];           // L2 merges to full lines
      if (bx != by)
        *(f16x4*)(sim + (size_t)C*NB + R0) = h;          // transpose mirror, 8B
    }
  }
}

// PASS 2: one row per WAVE, no atomics. Wave loads its whole row (64 fp16/lane,
// 8 independent 16B loads), phase A reduce (butterfly leaves totals in every
// lane -> wave-uniform thresholds for free), phase B over the same registers,
// LDS-reduce the 4 wave losses, ONE plain store per block.
__global__ __launch_bounds__(256) void row_stats(const _Float16* sim, const unsigned char* lab8,
                                                 float* blockLoss){
  __shared__ unsigned char slab[NB];   // 4 KB: all labels as bytes
  __shared__ float wloss[4];
  const int tid  = threadIdx.x;
  *(int4*)&slab[tid*16] = *(const int4*)&lab8[tid*16];
  __syncthreads();

  const int lane = tid & 63;
  const int wv   = tid >> 6;
  const int r    = blockIdx.x * 4 + wv;
  const int labR = (int)slab[r];                    // wave-uniform
  const _Float16* rowp = sim + (size_t)r * NB;

  // load whole row: chunk c covers cols c*512 + lane*8 .. +7
  f16x8 h[8];
  unsigned long long lb[8];
#pragma unroll
  for (int c=0;c<8;++c)
    h[c] = *(const f16x8*)(rowp + c*512 + lane*8);
#pragma unroll
  for (int c=0;c<8;++c)
    lb[c] = *(const unsigned long long*)&slab[c*512 + lane*8];

  // phase A: sum, min_pos (same & <1-eps), max_neg (diff)
  float s = 0.f, mp = 3.0e38f, mn = -3.0e38f;
#pragma unroll
  for (int c=0;c<8;++c){
    const unsigned long long L = lb[c];
#pragma unroll
    for (int j=0;j<8;++j){
      const float x = (float)h[c][j];
      const int lj = (int)((L >> (8*j)) & 0xffULL);
      s += x;
      if (lj == labR){ if (x < 0.99999f) mp = fminf(mp, x); }
      else           { mn = fmaxf(mn, x); }
    }
  }
#pragma unroll
  for (int o=1;o<64;o<<=1){
    s  += __shfl_xor(s, o, 64);
    mp  = fminf(mp, __shfl_xor(mp, o, 64));
    mn  = fmaxf(mn, __shfl_xor(mn, o, 64));
  }
  const bool hp = (mp < 1.0e38f), hn = (mn > -1.0e38f);
  const float mpr = hp ? mp : 1.0e9f;               // BIG like reference
  const float mnr = hn ? mn : -1.0e9f;
  const float mean_ = (s * (1.0f/(float)NB) + 0.5f*(mpr+mnr)) * 0.5f;
  const float tpp = mnr + 0.1f;                     // pp: x < max_neg + MARGIN
  const float tnm = mpr - 0.1f;                     // nm: x > min_pos - MARGIN

  // phase B: sigma, fp, fn from the same registers
  float sg = 0.f, fps = 0.f, fns = 0.f;
#pragma unroll
  for (int c=0;c<8;++c){
    const unsigned long long L = lb[c];
#pragma unroll
    for (int j=0;j<8;++j){
      const float x = (float)h[c][j];
      const int lj = (int)((L >> (8*j)) & 0xffULL);
      if (lj != labR){
        const float d = x - mean_; sg += d*d;
        if (x > tnm) fns += __expf((x - 0.5f) * 40.0f);
      } else if (x < 0.99999f && x < tpp){
        fps += __expf(-(x - 0.5f) * 2.0f);
      }
    }
  }
#pragma unroll
  for (int o=1;o<64;o<<=1){
    sg  += __shfl_xor(sg,  o, 64);
    fps += __shfl_xor(fps, o, 64);
    fns += __shfl_xor(fns, o, 64);
  }

  if (lane == 0){
    wloss[wv] = (hp && hn && fps > 0.f && fns > 0.f)
                ? (logf(1.f + fps) + logf(1.f + fns) + 0.1f * sg) : 0.f;
  }
  __syncthreads();
  if (tid == 0)
    blockLoss[blockIdx.x] = wloss[0] + wloss[1] + wloss[2] + wloss[3];
}

__global__ __launch_bounds__(1024) void finalize(const float* blockLoss, float* out){
  const int tid = threadIdx.x;
  float l = blockLoss[tid];          // exactly NB/4 == 1024 entries
#pragma unroll
  for (int o=1;o<64;o<<=1) l += __shfl_xor(l, o, 64);
  __shared__ float red[16];
  if ((tid & 63) == 0) red[tid >> 6] = l;
  __syncthreads();
  if (tid == 0){
    float t = 0.f;
#pragma unroll
    for (int i=0;i<16;++i) t += red[i];
    out[0] = t * (1.0f/(float)NB);
  }
}

extern "C" void kernel_launch(void* const* d_in, const int* in_sizes, int n_in,
                              void* d_out, int out_size, void* d_ws, size_t ws_size,
                              hipStream_t stream) {
  (void)in_sizes; (void)n_in; (void)out_size; (void)ws_size;
  const float* feats  = (const float*)d_in[0];
  const int*   labels = (const int*)d_in[1];
  float* out = (float*)d_out;

  // ws layout: sim fp16 (32MB) | fb bf16 (4MB) | lab8 (4KB) | blockLoss (4KB)
  _Float16* sim       = (_Float16*)d_ws;
  unsigned short* fb  = (unsigned short*)(sim + (size_t)NB*NB);
  unsigned char* lab8 = (unsigned char*)(fb + (size_t)NB*ND);
  float* blockLoss    = (float*)(lab8 + NB);

  convert_init<<<dim3((NB*ND/8)/256), dim3(256), 0, stream>>>(feats, fb, labels, lab8);

  gemm_sim<<<dim3(528), dim3(256), 0, stream>>>(fb, sim);

  row_stats<<<dim3(NB/4), dim3(256), 0, stream>>>(sim, lab8, blockLoss);

  finalize<<<dim3(1), dim3(1024), 0, stream>>>(blockLoss, out);
}